// Round 1
// baseline (876.968 us; speedup 1.0000x reference)
//
#include <hip/hip_runtime.h>
#include <hip/hip_bf16.h>
#include <cstddef>

// ---------------------------------------------------------------------------
// Model constants
// ---------------------------------------------------------------------------
#define S_LEN 1024
#define D_DIM 128
#define H_HEADS 8
#define DH_DIM 16
#define FF_DIM 2048
#define L_LAYERS 4
#define HID_DIM 768
#define LN_EPS 1e-5f

// ---------------------------------------------------------------------------
// Kernel 1: embeddings + motion MLP + focus linear + positional add -> x[S,D]
// grid: S blocks, 128 threads
// ---------------------------------------------------------------------------
__global__ __launch_bounds__(128) void embed_kernel(
    const int* __restrict__ shot, const int* __restrict__ cam,
    const int* __restrict__ light, const int* __restrict__ tone,
    const int* __restrict__ rhythm, const int* __restrict__ trans,
    const float* __restrict__ motion, const float* __restrict__ focus,
    const float* __restrict__ E_shot, const float* __restrict__ E_cam,
    const float* __restrict__ E_light, const float* __restrict__ E_tone,
    const float* __restrict__ E_rhythm, const float* __restrict__ E_trans,
    const float* __restrict__ W_m1, const float* __restrict__ b_m1,
    const float* __restrict__ W_m2, const float* __restrict__ b_m2,
    const float* __restrict__ W_f, const float* __restrict__ b_f,
    const float* __restrict__ pos, float* __restrict__ x)
{
    const int s = blockIdx.x;
    const int d = threadIdx.x;           // 0..127

    // motion params (broadcast loads, all threads read same 4+2 floats)
    const float m0 = motion[s * 4 + 0];
    const float m1 = motion[s * 4 + 1];
    const float m2 = motion[s * 4 + 2];
    const float m3 = motion[s * 4 + 3];
    const float f0 = focus[s * 2 + 0];
    const float f1 = focus[s * 2 + 1];

    // hidden layer of motion MLP: h[64] = relu(W_m1 @ m + b_m1)
    __shared__ float h[64];
    if (d < 64) {
        float a = b_m1[d];
        a += W_m1[d * 4 + 0] * m0;
        a += W_m1[d * 4 + 1] * m1;
        a += W_m1[d * 4 + 2] * m2;
        a += W_m1[d * 4 + 3] * m3;
        h[d] = fmaxf(a, 0.0f);
    }
    __syncthreads();

    // motion_emb[d] = W_m2[d,:] @ h + b_m2[d]
    float acc = b_m2[d];
    const float* wrow = W_m2 + (size_t)d * 64;
    #pragma unroll
    for (int k = 0; k < 64; k += 4) {
        float4 w4 = *reinterpret_cast<const float4*>(wrow + k);
        acc += w4.x * h[k] + w4.y * h[k + 1] + w4.z * h[k + 2] + w4.w * h[k + 3];
    }

    // focus linear
    acc += b_f[d] + W_f[d * 2 + 0] * f0 + W_f[d * 2 + 1] * f1;

    // categorical embeddings
    acc += E_shot  [(size_t)shot[s]   * D_DIM + d];
    acc += E_cam   [(size_t)cam[s]    * D_DIM + d];
    acc += E_light [(size_t)light[s]  * D_DIM + d];
    acc += E_tone  [(size_t)tone[s]   * D_DIM + d];
    acc += E_rhythm[(size_t)rhythm[s] * D_DIM + d];
    acc += E_trans [(size_t)trans[s]  * D_DIM + d];

    // positional
    acc += pos[(size_t)s * D_DIM + d];

    x[(size_t)s * D_DIM + d] = acc;
}

// ---------------------------------------------------------------------------
// Generic fp32 GEMM: C[M,N] = A[M,K] @ W[N,K]^T + bias[N], optional ReLU.
// Both A and W are K-major (torch [out,in] weight layout) -> dot-product GEMM.
// Block: 256 threads, 32x32 output tile, BK=128 LDS staging, +4 pad to break
// the 512B-stride bank conflict (2-way residual aliasing = free, m136).
// ---------------------------------------------------------------------------
__global__ __launch_bounds__(256) void gemm_kernel(
    const float* __restrict__ A, const float* __restrict__ W,
    const float* __restrict__ bias, float* __restrict__ C,
    int M, int N, int K, int do_relu)
{
    __shared__ float As[32][132];
    __shared__ float Ws[32][132];

    const int t  = threadIdx.x;
    const int m0 = blockIdx.y * 32;
    const int n0 = blockIdx.x * 32;

    const int tr = t >> 4;          // 0..15 (row in micro layout)
    const int tc = t & 15;          // 0..15 (col)
    const int lrow = t >> 5;        // 0..7  (staging row base)
    const int lcol = (t & 31) * 4;  // 0..124 (staging col, float4)

    float acc00 = 0.f, acc01 = 0.f, acc10 = 0.f, acc11 = 0.f;

    for (int k0 = 0; k0 < K; k0 += 128) {
        #pragma unroll
        for (int l = 0; l < 4; ++l) {
            const int r = lrow + l * 8;
            float4 va = *reinterpret_cast<const float4*>(
                &A[(size_t)(m0 + r) * K + k0 + lcol]);
            *reinterpret_cast<float4*>(&As[r][lcol]) = va;
            float4 vw = *reinterpret_cast<const float4*>(
                &W[(size_t)(n0 + r) * K + k0 + lcol]);
            *reinterpret_cast<float4*>(&Ws[r][lcol]) = vw;
        }
        __syncthreads();

        #pragma unroll
        for (int k = 0; k < 128; k += 4) {
            float4 a0 = *reinterpret_cast<const float4*>(&As[tr][k]);
            float4 a1 = *reinterpret_cast<const float4*>(&As[tr + 16][k]);
            float4 w0 = *reinterpret_cast<const float4*>(&Ws[tc][k]);
            float4 w1 = *reinterpret_cast<const float4*>(&Ws[tc + 16][k]);
            acc00 += a0.x * w0.x + a0.y * w0.y + a0.z * w0.z + a0.w * w0.w;
            acc01 += a0.x * w1.x + a0.y * w1.y + a0.z * w1.z + a0.w * w1.w;
            acc10 += a1.x * w0.x + a1.y * w0.y + a1.z * w0.z + a1.w * w0.w;
            acc11 += a1.x * w1.x + a1.y * w1.y + a1.z * w1.z + a1.w * w1.w;
        }
        __syncthreads();
    }

    const int m = m0 + tr;
    const int n = n0 + tc;
    const float b0 = bias[n];
    const float b1 = bias[n + 16];
    float c00 = acc00 + b0, c01 = acc01 + b1;
    float c10 = acc10 + b0, c11 = acc11 + b1;
    if (do_relu) {
        c00 = fmaxf(c00, 0.f); c01 = fmaxf(c01, 0.f);
        c10 = fmaxf(c10, 0.f); c11 = fmaxf(c11, 0.f);
    }
    C[(size_t)m * N + n]             = c00;
    C[(size_t)m * N + n + 16]        = c01;
    C[(size_t)(m + 16) * N + n]      = c10;
    C[(size_t)(m + 16) * N + n + 16] = c11;
}

// ---------------------------------------------------------------------------
// Attention (fp32): per wave, one query row over all 1024 keys.
// qkv layout: [S, 3*D]; head h slices at h*16 (q), 128+h*16 (k), 256+h*16 (v).
// grid: (S/4, H), block 256 (4 waves).
// ---------------------------------------------------------------------------
__global__ __launch_bounds__(256) void attn_kernel(
    const float* __restrict__ qkv, float* __restrict__ o)
{
    __shared__ float p_lds[4][S_LEN];

    const int h    = blockIdx.y;
    const int wv   = threadIdx.x >> 6;
    const int lane = threadIdx.x & 63;
    const int qrow = blockIdx.x * 4 + wv;
    const float scale = 0.25f;  // 1/sqrt(16)

    // q row (scaled)
    float q[16];
    const float* qp = qkv + (size_t)qrow * 384 + h * 16;
    #pragma unroll
    for (int d = 0; d < 16; d += 4) {
        float4 v = *reinterpret_cast<const float4*>(qp + d);
        q[d] = v.x * scale; q[d + 1] = v.y * scale;
        q[d + 2] = v.z * scale; q[d + 3] = v.w * scale;
    }

    // scores: lane handles keys lane + 64*i
    const float* Kb = qkv + 128 + h * 16;
    float s[16];
    #pragma unroll
    for (int i = 0; i < 16; ++i) {
        const float* kp = Kb + (size_t)(lane + 64 * i) * 384;
        float a = 0.f;
        #pragma unroll
        for (int d = 0; d < 16; d += 4) {
            float4 kv = *reinterpret_cast<const float4*>(kp + d);
            a += q[d] * kv.x + q[d + 1] * kv.y + q[d + 2] * kv.z + q[d + 3] * kv.w;
        }
        s[i] = a;
    }

    // softmax over 1024 scores (16/lane x 64 lanes)
    float mx = s[0];
    #pragma unroll
    for (int i = 1; i < 16; ++i) mx = fmaxf(mx, s[i]);
    #pragma unroll
    for (int off = 32; off >= 1; off >>= 1) mx = fmaxf(mx, __shfl_xor(mx, off));
    float sum = 0.f;
    #pragma unroll
    for (int i = 0; i < 16; ++i) { s[i] = __expf(s[i] - mx); sum += s[i]; }
    #pragma unroll
    for (int off = 32; off >= 1; off >>= 1) sum += __shfl_xor(sum, off);
    const float inv = 1.f / sum;

    // stash p row in LDS (lane + 64*i: conflict-free, 2 lanes/bank)
    #pragma unroll
    for (int i = 0; i < 16; ++i) p_lds[wv][lane + 64 * i] = s[i];

    // PV: lane -> (group g of 256 keys, output dim d); staggered p reads so the
    // 4 groups hit 4 distinct banks; V reads coalesce 64B per 16-lane group.
    const int g = lane >> 4;
    const int d = lane & 15;
    const float* Vb = qkv + 256 + h * 16 + d;
    const int kb = g * 256;
    float acc = 0.f;
    #pragma unroll 8
    for (int j = 0; j < 256; ++j) {
        const int kk = kb + ((j + g * 8) & 255);
        acc += p_lds[wv][kk] * Vb[(size_t)kk * 384];
    }
    acc += __shfl_xor(acc, 16);
    acc += __shfl_xor(acc, 32);
    if (lane < 16)
        o[(size_t)qrow * D_DIM + h * 16 + lane] = acc * inv;
}

// ---------------------------------------------------------------------------
// x = LayerNorm(x + c) * g + b   (row = 128 elements, in place on x)
// grid: S blocks, 128 threads
// ---------------------------------------------------------------------------
__global__ __launch_bounds__(128) void add_ln_kernel(
    float* __restrict__ x, const float* __restrict__ c,
    const float* __restrict__ g, const float* __restrict__ b)
{
    const int srow = blockIdx.x;
    const int d = threadIdx.x;
    const size_t idx = (size_t)srow * D_DIM + d;

    float v = x[idx] + c[idx];

    __shared__ float red[2];
    const int wv = d >> 6, ln = d & 63;

    float sum = v;
    #pragma unroll
    for (int off = 32; off >= 1; off >>= 1) sum += __shfl_xor(sum, off);
    if (ln == 0) red[wv] = sum;
    __syncthreads();
    const float mu = (red[0] + red[1]) * (1.0f / 128.0f);

    const float dv = v - mu;
    float sq = dv * dv;
    #pragma unroll
    for (int off = 32; off >= 1; off >>= 1) sq += __shfl_xor(sq, off);
    __syncthreads();             // red reuse
    if (ln == 0) red[wv] = sq;
    __syncthreads();
    const float var = (red[0] + red[1]) * (1.0f / 128.0f);

    x[idx] = dv * rsqrtf(var + LN_EPS) * g[d] + b[d];
}

// ---------------------------------------------------------------------------
// boundary_mask zeros
// ---------------------------------------------------------------------------
__global__ void zero_kernel(float* __restrict__ p, int n)
{
    const int i = blockIdx.x * blockDim.x + threadIdx.x;
    if (i < n) p[i] = 0.0f;
}

// ---------------------------------------------------------------------------
// Host launch
// ---------------------------------------------------------------------------
extern "C" void kernel_launch(void* const* d_in, const int* in_sizes, int n_in,
                              void* d_out, int out_size, void* d_ws, size_t ws_size,
                              hipStream_t stream)
{
    // Inputs in setup_inputs() dict order
    const int*   shot    = (const int*)  d_in[0];
    const int*   cam     = (const int*)  d_in[1];
    const int*   light   = (const int*)  d_in[2];
    const int*   tone    = (const int*)  d_in[3];
    const int*   rhythm  = (const int*)  d_in[4];
    const int*   trans   = (const int*)  d_in[5];
    const float* motion  = (const float*)d_in[6];
    const float* focus   = (const float*)d_in[7];
    const float* E_shot  = (const float*)d_in[8];
    const float* E_cam   = (const float*)d_in[9];
    const float* E_light = (const float*)d_in[10];
    const float* E_tone  = (const float*)d_in[11];
    const float* E_rhyth = (const float*)d_in[12];
    const float* E_trans = (const float*)d_in[13];
    const float* W_m1    = (const float*)d_in[14];
    const float* b_m1    = (const float*)d_in[15];
    const float* W_m2    = (const float*)d_in[16];
    const float* b_m2    = (const float*)d_in[17];
    const float* W_f     = (const float*)d_in[18];
    const float* b_f     = (const float*)d_in[19];
    const float* pos     = (const float*)d_in[20];
    const float* Wqkv    = (const float*)d_in[21];
    const float* bqkv    = (const float*)d_in[22];
    const float* Wo      = (const float*)d_in[23];
    const float* bo      = (const float*)d_in[24];
    const float* W1      = (const float*)d_in[25];
    const float* b1      = (const float*)d_in[26];
    const float* W2      = (const float*)d_in[27];
    const float* b2      = (const float*)d_in[28];
    const float* ln1_g   = (const float*)d_in[29];
    const float* ln1_b   = (const float*)d_in[30];
    const float* ln2_g   = (const float*)d_in[31];
    const float* ln2_b   = (const float*)d_in[32];
    const float* W_out   = (const float*)d_in[33];
    const float* b_out   = (const float*)d_in[34];

    float* out = (float*)d_out;

    // workspace layout (floats)
    float* ws   = (float*)d_ws;
    float* x    = ws;                              // 1024*128  = 131072
    float* qkv  = x    + S_LEN * D_DIM;            // 1024*384  = 393216
    float* attn = qkv  + S_LEN * 3 * D_DIM;        // 1024*128
    float* proj = attn + S_LEN * D_DIM;            // 1024*128 (reused for ff2)
    float* hbuf = proj + S_LEN * D_DIM;            // 1024*2048 = 2097152
    // total ~11.5 MB

    embed_kernel<<<S_LEN, 128, 0, stream>>>(
        shot, cam, light, tone, rhythm, trans, motion, focus,
        E_shot, E_cam, E_light, E_tone, E_rhyth, E_trans,
        W_m1, b_m1, W_m2, b_m2, W_f, b_f, pos, x);

    for (int i = 0; i < L_LAYERS; ++i) {
        const float* Wqkv_i = Wqkv + (size_t)i * 3 * D_DIM * D_DIM;
        const float* bqkv_i = bqkv + (size_t)i * 3 * D_DIM;
        const float* Wo_i   = Wo   + (size_t)i * D_DIM * D_DIM;
        const float* bo_i   = bo   + (size_t)i * D_DIM;
        const float* W1_i   = W1   + (size_t)i * FF_DIM * D_DIM;
        const float* b1_i   = b1   + (size_t)i * FF_DIM;
        const float* W2_i   = W2   + (size_t)i * D_DIM * FF_DIM;
        const float* b2_i   = b2   + (size_t)i * D_DIM;

        // qkv = x @ Wqkv^T + bqkv     [1024, 384]
        gemm_kernel<<<dim3(3 * D_DIM / 32, S_LEN / 32), 256, 0, stream>>>(
            x, Wqkv_i, bqkv_i, qkv, S_LEN, 3 * D_DIM, D_DIM, 0);

        // attn = softmax(qk)v         [1024, 128]
        attn_kernel<<<dim3(S_LEN / 4, H_HEADS), 256, 0, stream>>>(qkv, attn);

        // proj = attn @ Wo^T + bo     [1024, 128]
        gemm_kernel<<<dim3(D_DIM / 32, S_LEN / 32), 256, 0, stream>>>(
            attn, Wo_i, bo_i, proj, S_LEN, D_DIM, D_DIM, 0);

        // x = LN(x + proj)
        add_ln_kernel<<<S_LEN, 128, 0, stream>>>(
            x, proj, ln1_g + (size_t)i * D_DIM, ln1_b + (size_t)i * D_DIM);

        // h = relu(x @ W1^T + b1)     [1024, 2048]
        gemm_kernel<<<dim3(FF_DIM / 32, S_LEN / 32), 256, 0, stream>>>(
            x, W1_i, b1_i, hbuf, S_LEN, FF_DIM, D_DIM, 1);

        // proj = h @ W2^T + b2        [1024, 128]
        gemm_kernel<<<dim3(D_DIM / 32, S_LEN / 32), 256, 0, stream>>>(
            hbuf, W2_i, b2_i, proj, S_LEN, D_DIM, FF_DIM, 0);

        // x = LN(x + proj)
        add_ln_kernel<<<S_LEN, 128, 0, stream>>>(
            x, proj, ln2_g + (size_t)i * D_DIM, ln2_b + (size_t)i * D_DIM);
    }

    // cond = x @ W_out^T + b_out     [1024, 768] -> d_out
    gemm_kernel<<<dim3(HID_DIM / 32, S_LEN / 32), 256, 0, stream>>>(
        x, W_out, b_out, out, S_LEN, HID_DIM, D_DIM, 0);

    // boundary_mask = zeros [1024]
    zero_kernel<<<1, 1024, 0, stream>>>(out + (size_t)S_LEN * HID_DIM, S_LEN);
}

// Round 2
// 353.400 us; speedup vs baseline: 2.4815x; 2.4815x over previous
//
#include <hip/hip_runtime.h>
#include <hip/hip_bf16.h>
#include <cstddef>
#include <math.h>

// ---------------------------------------------------------------------------
// Model constants
// ---------------------------------------------------------------------------
#define S_LEN 1024
#define D_DIM 128
#define H_HEADS 8
#define DH_DIM 16
#define FF_DIM 2048
#define L_LAYERS 4
#define HID_DIM 768
#define LN_EPS 1e-5f

#define KSPLIT 8
#define KCH (S_LEN / KSPLIT)     // 128 keys per chunk
#define FF2_SPLIT 4              // split-K for FF2 (K=2048 -> 512 each)

// ---------------------------------------------------------------------------
// Kernel 1: embeddings + motion MLP + focus linear + positional add -> x[S,D]
// ---------------------------------------------------------------------------
__global__ __launch_bounds__(128) void embed_kernel(
    const int* __restrict__ shot, const int* __restrict__ cam,
    const int* __restrict__ light, const int* __restrict__ tone,
    const int* __restrict__ rhythm, const int* __restrict__ trans,
    const float* __restrict__ motion, const float* __restrict__ focus,
    const float* __restrict__ E_shot, const float* __restrict__ E_cam,
    const float* __restrict__ E_light, const float* __restrict__ E_tone,
    const float* __restrict__ E_rhythm, const float* __restrict__ E_trans,
    const float* __restrict__ W_m1, const float* __restrict__ b_m1,
    const float* __restrict__ W_m2, const float* __restrict__ b_m2,
    const float* __restrict__ W_f, const float* __restrict__ b_f,
    const float* __restrict__ pos, float* __restrict__ x)
{
    const int s = blockIdx.x;
    const int d = threadIdx.x;           // 0..127

    const float m0 = motion[s * 4 + 0];
    const float m1 = motion[s * 4 + 1];
    const float m2 = motion[s * 4 + 2];
    const float m3 = motion[s * 4 + 3];
    const float f0 = focus[s * 2 + 0];
    const float f1 = focus[s * 2 + 1];

    __shared__ float h[64];
    if (d < 64) {
        float a = b_m1[d];
        a += W_m1[d * 4 + 0] * m0;
        a += W_m1[d * 4 + 1] * m1;
        a += W_m1[d * 4 + 2] * m2;
        a += W_m1[d * 4 + 3] * m3;
        h[d] = fmaxf(a, 0.0f);
    }
    __syncthreads();

    float acc = b_m2[d];
    const float* wrow = W_m2 + (size_t)d * 64;
    #pragma unroll
    for (int k = 0; k < 64; k += 4) {
        float4 w4 = *reinterpret_cast<const float4*>(wrow + k);
        acc += w4.x * h[k] + w4.y * h[k + 1] + w4.z * h[k + 2] + w4.w * h[k + 3];
    }

    acc += b_f[d] + W_f[d * 2 + 0] * f0 + W_f[d * 2 + 1] * f1;

    acc += E_shot  [(size_t)shot[s]   * D_DIM + d];
    acc += E_cam   [(size_t)cam[s]    * D_DIM + d];
    acc += E_light [(size_t)light[s]  * D_DIM + d];
    acc += E_tone  [(size_t)tone[s]   * D_DIM + d];
    acc += E_rhythm[(size_t)rhythm[s] * D_DIM + d];
    acc += E_trans [(size_t)trans[s]  * D_DIM + d];

    acc += pos[(size_t)s * D_DIM + d];

    x[(size_t)s * D_DIM + d] = acc;
}

// ---------------------------------------------------------------------------
// gemm64: C[M,N] = A[M,128] @ W[N,128]^T + bias, optional ReLU.  K fixed 128.
// 64x64 tile, 256 threads, 4x4 micro at stride 16 (keeps LDS reads at
// free 2-way bank aliasing with the +4 pad). Single staging phase (K=128).
// LDS = 2 * 64*132*4 = 66 KB -> 2 blocks/CU.
// ---------------------------------------------------------------------------
__global__ __launch_bounds__(256) void gemm64_kernel(
    const float* __restrict__ A, const float* __restrict__ W,
    const float* __restrict__ bias, float* __restrict__ C,
    int M, int N, int do_relu)
{
    __shared__ float As[64][132];
    __shared__ float Ws[64][132];

    const int t  = threadIdx.x;
    const int n0 = blockIdx.x * 64;
    const int m0 = blockIdx.y * 64;

    #pragma unroll
    for (int l = 0; l < 8; ++l) {
        const int idx = t + l * 256;          // 0..2047
        const int row = idx >> 5;             // 0..63
        const int c4  = (idx & 31) * 4;       // 0..124
        *reinterpret_cast<float4*>(&As[row][c4]) =
            *reinterpret_cast<const float4*>(&A[(size_t)(m0 + row) * 128 + c4]);
        *reinterpret_cast<float4*>(&Ws[row][c4]) =
            *reinterpret_cast<const float4*>(&W[(size_t)(n0 + row) * 128 + c4]);
    }
    __syncthreads();

    const int tr = t >> 4;     // 0..15
    const int tc = t & 15;     // 0..15

    float acc[4][4];
    #pragma unroll
    for (int i = 0; i < 4; ++i)
        #pragma unroll
        for (int j = 0; j < 4; ++j) acc[i][j] = 0.f;

    #pragma unroll 8
    for (int k = 0; k < 128; k += 4) {
        float4 a[4], w[4];
        #pragma unroll
        for (int i = 0; i < 4; ++i)
            a[i] = *reinterpret_cast<const float4*>(&As[tr + 16 * i][k]);
        #pragma unroll
        for (int j = 0; j < 4; ++j)
            w[j] = *reinterpret_cast<const float4*>(&Ws[tc + 16 * j][k]);
        #pragma unroll
        for (int i = 0; i < 4; ++i)
            #pragma unroll
            for (int j = 0; j < 4; ++j)
                acc[i][j] += a[i].x * w[j].x + a[i].y * w[j].y
                           + a[i].z * w[j].z + a[i].w * w[j].w;
    }

    #pragma unroll
    for (int i = 0; i < 4; ++i) {
        const int m = m0 + tr + 16 * i;
        #pragma unroll
        for (int j = 0; j < 4; ++j) {
            const int n = n0 + tc + 16 * j;
            float v = acc[i][j] + bias[n];
            if (do_relu) v = fmaxf(v, 0.f);
            C[(size_t)m * N + n] = v;
        }
    }
}

// ---------------------------------------------------------------------------
// gemm32: 32x32 tile, 2x2 micro (round-1 kernel). Used for Wo (N=128,K=128).
// ---------------------------------------------------------------------------
__global__ __launch_bounds__(256) void gemm32_kernel(
    const float* __restrict__ A, const float* __restrict__ W,
    const float* __restrict__ bias, float* __restrict__ C,
    int M, int N, int K)
{
    __shared__ float As[32][132];
    __shared__ float Ws[32][132];

    const int t  = threadIdx.x;
    const int m0 = blockIdx.y * 32;
    const int n0 = blockIdx.x * 32;

    const int tr = t >> 4;
    const int tc = t & 15;
    const int lrow = t >> 5;
    const int lcol = (t & 31) * 4;

    float acc00 = 0.f, acc01 = 0.f, acc10 = 0.f, acc11 = 0.f;

    for (int k0 = 0; k0 < K; k0 += 128) {
        #pragma unroll
        for (int l = 0; l < 4; ++l) {
            const int r = lrow + l * 8;
            *reinterpret_cast<float4*>(&As[r][lcol]) =
                *reinterpret_cast<const float4*>(&A[(size_t)(m0 + r) * K + k0 + lcol]);
            *reinterpret_cast<float4*>(&Ws[r][lcol]) =
                *reinterpret_cast<const float4*>(&W[(size_t)(n0 + r) * K + k0 + lcol]);
        }
        __syncthreads();

        #pragma unroll 8
        for (int k = 0; k < 128; k += 4) {
            float4 a0 = *reinterpret_cast<const float4*>(&As[tr][k]);
            float4 a1 = *reinterpret_cast<const float4*>(&As[tr + 16][k]);
            float4 w0 = *reinterpret_cast<const float4*>(&Ws[tc][k]);
            float4 w1 = *reinterpret_cast<const float4*>(&Ws[tc + 16][k]);
            acc00 += a0.x * w0.x + a0.y * w0.y + a0.z * w0.z + a0.w * w0.w;
            acc01 += a0.x * w1.x + a0.y * w1.y + a0.z * w1.z + a0.w * w1.w;
            acc10 += a1.x * w0.x + a1.y * w0.y + a1.z * w0.z + a1.w * w0.w;
            acc11 += a1.x * w1.x + a1.y * w1.y + a1.z * w1.z + a1.w * w1.w;
        }
        __syncthreads();
    }

    const int m = m0 + tr;
    const int n = n0 + tc;
    const float b0 = bias[n];
    const float b1 = bias[n + 16];
    C[(size_t)m * N + n]             = acc00 + b0;
    C[(size_t)m * N + n + 16]        = acc01 + b1;
    C[(size_t)(m + 16) * N + n]      = acc10 + b0;
    C[(size_t)(m + 16) * N + n + 16] = acc11 + b1;
}

// ---------------------------------------------------------------------------
// gemm32sk: split-K partial GEMM for FF2. P[z][M,N] = A[:,kz] @ W[:,kz]^T.
// grid (N/32, M/32, FF2_SPLIT), no bias (folded into add_ln).
// ---------------------------------------------------------------------------
__global__ __launch_bounds__(256) void gemm32sk_kernel(
    const float* __restrict__ A, const float* __restrict__ W,
    float* __restrict__ P, int M, int N, int K)
{
    __shared__ float As[32][132];
    __shared__ float Ws[32][132];

    const int t  = threadIdx.x;
    const int m0 = blockIdx.y * 32;
    const int n0 = blockIdx.x * 32;
    const int kc = K / FF2_SPLIT;
    const int kbeg = blockIdx.z * kc;

    const int tr = t >> 4;
    const int tc = t & 15;
    const int lrow = t >> 5;
    const int lcol = (t & 31) * 4;

    float acc00 = 0.f, acc01 = 0.f, acc10 = 0.f, acc11 = 0.f;

    for (int k0 = kbeg; k0 < kbeg + kc; k0 += 128) {
        #pragma unroll
        for (int l = 0; l < 4; ++l) {
            const int r = lrow + l * 8;
            *reinterpret_cast<float4*>(&As[r][lcol]) =
                *reinterpret_cast<const float4*>(&A[(size_t)(m0 + r) * K + k0 + lcol]);
            *reinterpret_cast<float4*>(&Ws[r][lcol]) =
                *reinterpret_cast<const float4*>(&W[(size_t)(n0 + r) * K + k0 + lcol]);
        }
        __syncthreads();

        #pragma unroll 8
        for (int k = 0; k < 128; k += 4) {
            float4 a0 = *reinterpret_cast<const float4*>(&As[tr][k]);
            float4 a1 = *reinterpret_cast<const float4*>(&As[tr + 16][k]);
            float4 w0 = *reinterpret_cast<const float4*>(&Ws[tc][k]);
            float4 w1 = *reinterpret_cast<const float4*>(&Ws[tc + 16][k]);
            acc00 += a0.x * w0.x + a0.y * w0.y + a0.z * w0.z + a0.w * w0.w;
            acc01 += a0.x * w1.x + a0.y * w1.y + a0.z * w1.z + a0.w * w1.w;
            acc10 += a1.x * w0.x + a1.y * w0.y + a1.z * w0.z + a1.w * w0.w;
            acc11 += a1.x * w1.x + a1.y * w1.y + a1.z * w1.z + a1.w * w1.w;
        }
        __syncthreads();
    }

    float* Pz = P + (size_t)blockIdx.z * M * N;
    const int m = m0 + tr;
    const int n = n0 + tc;
    Pz[(size_t)m * N + n]             = acc00;
    Pz[(size_t)m * N + n + 16]        = acc01;
    Pz[(size_t)(m + 16) * N + n]      = acc10;
    Pz[(size_t)(m + 16) * N + n + 16] = acc11;
}

// ---------------------------------------------------------------------------
// Attention, split-K flash style. Each lane owns one q row; K/V chunk staged
// in LDS; all K/V reads are wave-broadcast; softmax fully lane-local.
// grid (KSPLIT, S/256, H), block 256.
// Partials: pm/pl [KSPLIT*H*S], po [KSPLIT*H*S*16].
// ---------------------------------------------------------------------------
__global__ __launch_bounds__(256) void attn_part_kernel(
    const float* __restrict__ qkv,
    float* __restrict__ pm, float* __restrict__ pl, float* __restrict__ po)
{
    __shared__ float Ks[KCH * 16];
    __shared__ float Vs[KCH * 16];

    const int t     = threadIdx.x;
    const int chunk = blockIdx.x;
    const int qb    = blockIdx.y;
    const int head  = blockIdx.z;
    const int kbase = chunk * KCH;

    // stage K,V chunk: 128 rows x 16 floats each
    #pragma unroll
    for (int l = 0; l < 2; ++l) {
        const int idx = t + l * 256;        // 0..511
        const int row = idx >> 2;
        const int c4  = (idx & 3) * 4;
        const float* src = qkv + (size_t)(kbase + row) * 384 + head * 16 + c4;
        *reinterpret_cast<float4*>(&Ks[row * 16 + c4]) =
            *reinterpret_cast<const float4*>(src + 128);
        *reinterpret_cast<float4*>(&Vs[row * 16 + c4]) =
            *reinterpret_cast<const float4*>(src + 256);
    }

    // own q row, pre-scaled
    const int qrow = qb * 256 + t;
    float q[16];
    {
        const float* qp = qkv + (size_t)qrow * 384 + head * 16;
        #pragma unroll
        for (int d = 0; d < 16; d += 4) {
            float4 v = *reinterpret_cast<const float4*>(qp + d);
            q[d] = v.x * 0.25f; q[d + 1] = v.y * 0.25f;
            q[d + 2] = v.z * 0.25f; q[d + 3] = v.w * 0.25f;
        }
    }
    __syncthreads();

    float m = -INFINITY, l = 0.f;
    float O[16];
    #pragma unroll
    for (int d = 0; d < 16; ++d) O[d] = 0.f;

    for (int j0 = 0; j0 < KCH; j0 += 8) {
        float s[8];
        #pragma unroll
        for (int jj = 0; jj < 8; ++jj) {
            const float* kr = &Ks[(j0 + jj) * 16];
            float a = 0.f;
            #pragma unroll
            for (int d = 0; d < 16; d += 4) {
                float4 kv = *reinterpret_cast<const float4*>(kr + d);
                a += q[d] * kv.x + q[d + 1] * kv.y + q[d + 2] * kv.z + q[d + 3] * kv.w;
            }
            s[jj] = a;
        }
        float bm = s[0];
        #pragma unroll
        for (int jj = 1; jj < 8; ++jj) bm = fmaxf(bm, s[jj]);
        const float mn = fmaxf(m, bm);
        const float corr = __expf(m - mn);   // exp(-inf)=0 on first batch
        m = mn;
        l *= corr;
        #pragma unroll
        for (int d = 0; d < 16; ++d) O[d] *= corr;
        #pragma unroll
        for (int jj = 0; jj < 8; ++jj) {
            const float p = __expf(s[jj] - m);
            l += p;
            const float* vr = &Vs[(j0 + jj) * 16];
            #pragma unroll
            for (int d = 0; d < 16; ++d) O[d] += p * vr[d];
        }
    }

    const int pidx = ((chunk * H_HEADS + head) << 10) + qrow;
    pm[pidx] = m;
    pl[pidx] = l;
    #pragma unroll
    for (int d = 0; d < 16; d += 4) {
        float4 v = make_float4(O[d], O[d + 1], O[d + 2], O[d + 3]);
        *reinterpret_cast<float4*>(&po[(size_t)pidx * 16 + d]) = v;
    }
}

// combine partials -> attn_out[S, D]
__global__ __launch_bounds__(256) void attn_comb_kernel(
    const float* __restrict__ pm, const float* __restrict__ pl,
    const float* __restrict__ po, float* __restrict__ o)
{
    const int gid  = blockIdx.x * 256 + threadIdx.x;   // 0..8191
    const int head = gid >> 10;
    const int row  = gid & 1023;

    float mg = -INFINITY;
    #pragma unroll
    for (int c = 0; c < KSPLIT; ++c)
        mg = fmaxf(mg, pm[((c * H_HEADS + head) << 10) + row]);

    float lg = 0.f;
    float O[16];
    #pragma unroll
    for (int d = 0; d < 16; ++d) O[d] = 0.f;

    #pragma unroll
    for (int c = 0; c < KSPLIT; ++c) {
        const int pidx = ((c * H_HEADS + head) << 10) + row;
        const float w = __expf(pm[pidx] - mg);
        lg += pl[pidx] * w;
        #pragma unroll
        for (int d = 0; d < 16; d += 4) {
            float4 v = *reinterpret_cast<const float4*>(&po[(size_t)pidx * 16 + d]);
            O[d] += w * v.x; O[d + 1] += w * v.y;
            O[d + 2] += w * v.z; O[d + 3] += w * v.w;
        }
    }

    const float inv = 1.f / lg;
    #pragma unroll
    for (int d = 0; d < 16; d += 4) {
        float4 v = make_float4(O[d] * inv, O[d + 1] * inv, O[d + 2] * inv, O[d + 3] * inv);
        *reinterpret_cast<float4*>(&o[(size_t)row * D_DIM + head * 16 + d]) = v;
    }
}

// ---------------------------------------------------------------------------
// x = LN(x + sum_p c[p] + bias) * g + b.  nparts partials at stride pstride.
// ---------------------------------------------------------------------------
__global__ __launch_bounds__(128) void add_ln_kernel(
    float* __restrict__ x, const float* __restrict__ c,
    int nparts, int pstride, const float* __restrict__ bias,
    const float* __restrict__ g, const float* __restrict__ b)
{
    const int srow = blockIdx.x;
    const int d = threadIdx.x;
    const size_t idx = (size_t)srow * D_DIM + d;

    float v = x[idx];
    for (int p = 0; p < nparts; ++p) v += c[idx + (size_t)p * pstride];
    if (bias) v += bias[d];

    __shared__ float red[2];
    const int wv = d >> 6, ln = d & 63;

    float sum = v;
    #pragma unroll
    for (int off = 32; off >= 1; off >>= 1) sum += __shfl_xor(sum, off);
    if (ln == 0) red[wv] = sum;
    __syncthreads();
    const float mu = (red[0] + red[1]) * (1.0f / 128.0f);

    const float dv = v - mu;
    float sq = dv * dv;
    #pragma unroll
    for (int off = 32; off >= 1; off >>= 1) sq += __shfl_xor(sq, off);
    __syncthreads();
    if (ln == 0) red[wv] = sq;
    __syncthreads();
    const float var = (red[0] + red[1]) * (1.0f / 128.0f);

    x[idx] = dv * rsqrtf(var + LN_EPS) * g[d] + b[d];
}

__global__ void zero_kernel(float* __restrict__ p, int n)
{
    const int i = blockIdx.x * blockDim.x + threadIdx.x;
    if (i < n) p[i] = 0.0f;
}

// ---------------------------------------------------------------------------
// Host launch
// ---------------------------------------------------------------------------
extern "C" void kernel_launch(void* const* d_in, const int* in_sizes, int n_in,
                              void* d_out, int out_size, void* d_ws, size_t ws_size,
                              hipStream_t stream)
{
    const int*   shot    = (const int*)  d_in[0];
    const int*   cam     = (const int*)  d_in[1];
    const int*   light   = (const int*)  d_in[2];
    const int*   tone    = (const int*)  d_in[3];
    const int*   rhythm  = (const int*)  d_in[4];
    const int*   trans   = (const int*)  d_in[5];
    const float* motion  = (const float*)d_in[6];
    const float* focus   = (const float*)d_in[7];
    const float* E_shot  = (const float*)d_in[8];
    const float* E_cam   = (const float*)d_in[9];
    const float* E_light = (const float*)d_in[10];
    const float* E_tone  = (const float*)d_in[11];
    const float* E_rhyth = (const float*)d_in[12];
    const float* E_trans = (const float*)d_in[13];
    const float* W_m1    = (const float*)d_in[14];
    const float* b_m1    = (const float*)d_in[15];
    const float* W_m2    = (const float*)d_in[16];
    const float* b_m2    = (const float*)d_in[17];
    const float* W_f     = (const float*)d_in[18];
    const float* b_f     = (const float*)d_in[19];
    const float* pos     = (const float*)d_in[20];
    const float* Wqkv    = (const float*)d_in[21];
    const float* bqkv    = (const float*)d_in[22];
    const float* Wo      = (const float*)d_in[23];
    const float* bo      = (const float*)d_in[24];
    const float* W1      = (const float*)d_in[25];
    const float* b1      = (const float*)d_in[26];
    const float* W2      = (const float*)d_in[27];
    const float* b2      = (const float*)d_in[28];
    const float* ln1_g   = (const float*)d_in[29];
    const float* ln1_b   = (const float*)d_in[30];
    const float* ln2_g   = (const float*)d_in[31];
    const float* ln2_b   = (const float*)d_in[32];
    const float* W_out   = (const float*)d_in[33];
    const float* b_out   = (const float*)d_in[34];

    float* out = (float*)d_out;

    // workspace layout (floats)
    float* ws   = (float*)d_ws;
    float* x    = ws;                              // 131072
    float* qkv  = x    + S_LEN * D_DIM;            // 393216
    float* attn = qkv  + S_LEN * 3 * D_DIM;        // 131072
    float* proj = attn + S_LEN * D_DIM;            // 131072
    float* hbuf = proj + S_LEN * D_DIM;            // 2097152
    // aliases (lifetimes disjoint):
    float* po   = hbuf;                            // 65536*16 (attn partials)
    float* pmb  = hbuf + 65536 * 16;               // 65536
    float* plb  = pmb + 65536;                     // 65536
    float* skp  = qkv;                             // FF2 partials: 4*131072 = 524288
                                                   //   (covers qkv+attn regions, both dead)

    embed_kernel<<<S_LEN, 128, 0, stream>>>(
        shot, cam, light, tone, rhythm, trans, motion, focus,
        E_shot, E_cam, E_light, E_tone, E_rhyth, E_trans,
        W_m1, b_m1, W_m2, b_m2, W_f, b_f, pos, x);

    for (int i = 0; i < L_LAYERS; ++i) {
        const float* Wqkv_i = Wqkv + (size_t)i * 3 * D_DIM * D_DIM;
        const float* bqkv_i = bqkv + (size_t)i * 3 * D_DIM;
        const float* Wo_i   = Wo   + (size_t)i * D_DIM * D_DIM;
        const float* bo_i   = bo   + (size_t)i * D_DIM;
        const float* W1_i   = W1   + (size_t)i * FF_DIM * D_DIM;
        const float* b1_i   = b1   + (size_t)i * FF_DIM;
        const float* W2_i   = W2   + (size_t)i * D_DIM * FF_DIM;
        const float* b2_i   = b2   + (size_t)i * D_DIM;

        // qkv = x @ Wqkv^T + bqkv   [1024, 384]
        gemm64_kernel<<<dim3(3 * D_DIM / 64, S_LEN / 64), 256, 0, stream>>>(
            x, Wqkv_i, bqkv_i, qkv, S_LEN, 3 * D_DIM, 0);

        // attention
        attn_part_kernel<<<dim3(KSPLIT, S_LEN / 256, H_HEADS), 256, 0, stream>>>(
            qkv, pmb, plb, po);
        attn_comb_kernel<<<dim3(S_LEN * H_HEADS / 256), 256, 0, stream>>>(
            pmb, plb, po, attn);

        // proj = attn @ Wo^T + bo   [1024, 128]
        gemm32_kernel<<<dim3(D_DIM / 32, S_LEN / 32), 256, 0, stream>>>(
            attn, Wo_i, bo_i, proj, S_LEN, D_DIM, D_DIM);

        // x = LN(x + proj)
        add_ln_kernel<<<S_LEN, 128, 0, stream>>>(
            x, proj, 1, 0, nullptr,
            ln1_g + (size_t)i * D_DIM, ln1_b + (size_t)i * D_DIM);

        // h = relu(x @ W1^T + b1)   [1024, 2048]
        gemm64_kernel<<<dim3(FF_DIM / 64, S_LEN / 64), 256, 0, stream>>>(
            x, W1_i, b1_i, hbuf, S_LEN, FF_DIM, 1);

        // FF2 split-K partials      [4][1024, 128]
        gemm32sk_kernel<<<dim3(D_DIM / 32, S_LEN / 32, FF2_SPLIT), 256, 0, stream>>>(
            hbuf, W2_i, skp, S_LEN, D_DIM, FF_DIM);

        // x = LN(x + sum partials + b2)
        add_ln_kernel<<<S_LEN, 128, 0, stream>>>(
            x, skp, FF2_SPLIT, S_LEN * D_DIM, b2_i,
            ln2_g + (size_t)i * D_DIM, ln2_b + (size_t)i * D_DIM);
    }

    // cond = x @ W_out^T + b_out   [1024, 768]
    gemm64_kernel<<<dim3(HID_DIM / 64, S_LEN / 64), 256, 0, stream>>>(
        x, W_out, b_out, out, S_LEN, HID_DIM, 0);

    // boundary_mask = zeros [1024]
    zero_kernel<<<1, 1024, 0, stream>>>(out + (size_t)S_LEN * HID_DIM, S_LEN);
}